// Round 1
// baseline (344.499 us; speedup 1.0000x reference)
//
#include <hip/hip_runtime.h>

// Round 0: correct bf16-MFMA pipeline.
//   gemm_bt<fp32 A -> bf16 qkv>  ->  rope_scatter (q,k rope'd; v transposed)
//   -> flash_attn (1 wave / 16 q-rows, 16x16x32 bf16 MFMA, online softmax)
//   -> gemm_bt<bf16 A -> fp32 out>
// ws layout (bytes): qkv 25165824 | q 8388608 | k 8388608 | vT 8388608 | o 8388608

typedef float f32x4 __attribute__((ext_vector_type(4)));
typedef float fvec4 __attribute__((ext_vector_type(4)));
typedef __bf16 bf16x8 __attribute__((ext_vector_type(8)));
typedef unsigned int u32x4 __attribute__((ext_vector_type(4)));

#define S_SZ 2048
#define NH 16
#define DK 64

static __device__ __forceinline__ unsigned short f2bf(float f) {
  unsigned int u = __builtin_bit_cast(unsigned int, f);
  u += 0x7fffu + ((u >> 16) & 1u);
  return (unsigned short)(u >> 16);
}
static __device__ __forceinline__ float bf2f(unsigned short h) {
  unsigned int u = ((unsigned int)h) << 16;
  return __builtin_bit_cast(float, u);
}
static __device__ __forceinline__ unsigned int pk2(float a, float b) {
  return (unsigned int)f2bf(a) | ((unsigned int)f2bf(b) << 16);
}
static __device__ __forceinline__ bf16x8 ld16g(const unsigned short* p) {
  return __builtin_bit_cast(bf16x8, *(const u32x4*)p);
}

// C[m][n] = sum_k A[m][k] * B[n][k] + bias[n]; A row-major (M,K) fp32 or bf16,
// B row-major (N,K) fp32, out bf16 or fp32. M%128==N%128==K%32==0.
template <bool ABF16, bool OBF16>
__global__ __launch_bounds__(256) void gemm_bt(const void* __restrict__ Ap,
                                               const float* __restrict__ Bp,
                                               const float* __restrict__ bias,
                                               void* __restrict__ Cp,
                                               int M, int N, int K) {
  __shared__ unsigned short As[128][40];  // pad 32->40: 80B row stride
  __shared__ unsigned short Bs[128][40];
  const int t = threadIdx.x;
  const int lane = t & 63;
  const int wid = t >> 6;
  const int wr = (wid >> 1) * 64, wc = (wid & 1) * 64;
  const int lo = lane & 15, g = lane >> 4;
  const int bRow = blockIdx.y * 128, bCol = blockIdx.x * 128;
  const int sr = t >> 1, sc = (t & 1) * 16;
  f32x4 acc[4][4] = {};
  for (int k0 = 0; k0 < K; k0 += 32) {
    // stage A tile (rows = output rows)
    if constexpr (ABF16) {
      const unsigned short* A16 = (const unsigned short*)Ap;
      const u32x4* ap = (const u32x4*)(A16 + (size_t)(bRow + sr) * K + k0 + sc);
      u32x4 v0 = ap[0], v1 = ap[1];
      *(u32x4*)&As[sr][sc] = v0;
      *(u32x4*)&As[sr][sc + 8] = v1;
    } else {
      const float* Af = (const float*)Ap;
      const fvec4* ap = (const fvec4*)(Af + (size_t)(bRow + sr) * K + k0 + sc);
      fvec4 f0 = ap[0], f1 = ap[1], f2 = ap[2], f3 = ap[3];
      u32x4 u0, u1;
      u0[0] = pk2(f0[0], f0[1]); u0[1] = pk2(f0[2], f0[3]);
      u0[2] = pk2(f1[0], f1[1]); u0[3] = pk2(f1[2], f1[3]);
      u1[0] = pk2(f2[0], f2[1]); u1[1] = pk2(f2[2], f2[3]);
      u1[2] = pk2(f3[0], f3[1]); u1[3] = pk2(f3[2], f3[3]);
      *(u32x4*)&As[sr][sc] = u0;
      *(u32x4*)&As[sr][sc + 8] = u1;
    }
    // stage B tile (rows = output cols; B is (N,K))
    {
      const fvec4* bp = (const fvec4*)(Bp + (size_t)(bCol + sr) * K + k0 + sc);
      fvec4 f0 = bp[0], f1 = bp[1], f2 = bp[2], f3 = bp[3];
      u32x4 u0, u1;
      u0[0] = pk2(f0[0], f0[1]); u0[1] = pk2(f0[2], f0[3]);
      u0[2] = pk2(f1[0], f1[1]); u0[3] = pk2(f1[2], f1[3]);
      u1[0] = pk2(f2[0], f2[1]); u1[1] = pk2(f2[2], f2[3]);
      u1[2] = pk2(f3[0], f3[1]); u1[3] = pk2(f3[2], f3[3]);
      *(u32x4*)&Bs[sr][sc] = u0;
      *(u32x4*)&Bs[sr][sc + 8] = u1;
    }
    __syncthreads();
    bf16x8 aF[4], bF[4];
#pragma unroll
    for (int m = 0; m < 4; ++m)
      aF[m] = __builtin_bit_cast(bf16x8, *(const u32x4*)&As[wr + m * 16 + lo][8 * g]);
#pragma unroll
    for (int n = 0; n < 4; ++n)
      bF[n] = __builtin_bit_cast(bf16x8, *(const u32x4*)&Bs[wc + n * 16 + lo][8 * g]);
#pragma unroll
    for (int m = 0; m < 4; ++m)
#pragma unroll
      for (int n = 0; n < 4; ++n)
        acc[m][n] = __builtin_amdgcn_mfma_f32_16x16x32_bf16(aF[m], bF[n], acc[m][n], 0, 0, 0);
    __syncthreads();
  }
  // epilogue: C row = (lane>>4)*4+reg, col = lane&15 within each 16x16 frag
#pragma unroll
  for (int m = 0; m < 4; ++m) {
#pragma unroll
    for (int n = 0; n < 4; ++n) {
      const int col = bCol + wc + n * 16 + lo;
      const float bv = bias[col];
#pragma unroll
      for (int r = 0; r < 4; ++r) {
        const int row = bRow + wr + m * 16 + g * 4 + r;
        const float v = acc[m][n][r] + bv;
        if constexpr (OBF16)
          ((unsigned short*)Cp)[(size_t)row * N + col] = f2bf(v);
        else
          ((float*)Cp)[(size_t)row * N + col] = v;
      }
    }
  }
}

// qkv (B*S, 3072) bf16 -> q,k rope'd [B,H,S,64] bf16 ; v -> vT [B,H,64,S] bf16
__global__ __launch_bounds__(256) void rope_scatter(
    const unsigned short* __restrict__ qkv, unsigned short* __restrict__ Qo,
    unsigned short* __restrict__ Ko, unsigned short* __restrict__ Vt) {
  const int t = blockIdx.x * 256 + threadIdx.x;  // 2^21 threads
  const int i = t & 31;                          // pair index 0..31
  const int s = (t >> 5) & (S_SZ - 1);
  const int h = (t >> 16) & (NH - 1);
  const int b = t >> 20;
  const unsigned short* row = qkv + (size_t)(b * S_SZ + s) * 3072;
  // inv_freq = 10000^(-i/32) = 2^(-i*log2(1e4)/32)
  const float inv = exp2f((float)i * (-13.287712379549449f / 32.0f));
  const float ang = (float)s * inv;
  float sn, cs;
  sincosf(ang, &sn, &cs);
  const unsigned int qp = *(const unsigned int*)(row + h * 64 + 2 * i);
  const unsigned int kp = *(const unsigned int*)(row + 1024 + h * 64 + 2 * i);
  const unsigned int vp = *(const unsigned int*)(row + 2048 + h * 64 + 2 * i);
  const float qe = bf2f((unsigned short)qp), qo = bf2f((unsigned short)(qp >> 16));
  const float ke = bf2f((unsigned short)kp), ko = bf2f((unsigned short)(kp >> 16));
  const size_t hb = (size_t)(b * NH + h);
  const size_t qkbase = (hb * S_SZ + s) * DK + 2 * i;
  *(unsigned int*)(Qo + qkbase) = pk2(qe * cs - qo * sn, qe * sn + qo * cs);
  *(unsigned int*)(Ko + qkbase) = pk2(ke * cs - ko * sn, ke * sn + ko * cs);
  const size_t vb = (hb * DK + 2 * i) * S_SZ + s;
  Vt[vb] = (unsigned short)vp;
  Vt[vb + S_SZ] = (unsigned short)(vp >> 16);
}

// 1 wave per 16 q-rows; K blocks of 64 keys; online softmax; P via wave-private LDS.
__global__ __launch_bounds__(256) void flash_attn(
    const unsigned short* __restrict__ Q, const unsigned short* __restrict__ K,
    const unsigned short* __restrict__ VT, unsigned short* __restrict__ O) {
  __shared__ unsigned short P_lds[4][16][72];  // per-wave 16x64 P tile, padded
  const int t = threadIdx.x;
  const int lane = t & 63, w = t >> 6;
  const int lo = lane & 15, g = lane >> 4;
  const int bh = blockIdx.y;  // b*16+h
  const int q0 = (blockIdx.x * 4 + w) * 16;
  const unsigned short* Qh = Q + (size_t)bh * S_SZ * DK;
  const unsigned short* Kh = K + (size_t)bh * S_SZ * DK;
  const unsigned short* Vh = VT + (size_t)bh * DK * S_SZ;
  // A-frag: lane holds Q[q0 + (lane&15)][8*(lane>>4)+i (+32)]
  const bf16x8 aQ0 = ld16g(Qh + (size_t)(q0 + lo) * DK + 8 * g);
  const bf16x8 aQ1 = ld16g(Qh + (size_t)(q0 + lo) * DK + 32 + 8 * g);
  f32x4 oacc[4] = {};
  float m[4], lsum[4];
#pragma unroll
  for (int r = 0; r < 4; ++r) { m[r] = -__builtin_inff(); lsum[r] = 0.f; }
  const int ktmax = (q0 + 15) >> 6;
  for (int kt = 0; kt <= ktmax; ++kt) {
    const int kbase = kt << 6;
    f32x4 s[4];
#pragma unroll
    for (int c = 0; c < 4; ++c) {
      const unsigned short* kr = Kh + (size_t)(kbase + c * 16 + lo) * DK + 8 * g;
      f32x4 z = {};
      z = __builtin_amdgcn_mfma_f32_16x16x32_bf16(aQ0, ld16g(kr), z, 0, 0, 0);
      z = __builtin_amdgcn_mfma_f32_16x16x32_bf16(aQ1, ld16g(kr + 32), z, 0, 0, 0);
      s[c] = z;
    }
    const bool diag = (kt == ktmax);
#pragma unroll
    for (int c = 0; c < 4; ++c)
#pragma unroll
      for (int r = 0; r < 4; ++r) {
        float v = s[c][r] * 0.125f;
        if (diag && (kbase + c * 16 + lo) > (q0 + g * 4 + r)) v = -__builtin_inff();
        s[c][r] = v;
      }
#pragma unroll
    for (int r = 0; r < 4; ++r) {
      float rm = fmaxf(fmaxf(s[0][r], s[1][r]), fmaxf(s[2][r], s[3][r]));
      rm = fmaxf(rm, __shfl_xor(rm, 1, 16));
      rm = fmaxf(rm, __shfl_xor(rm, 2, 16));
      rm = fmaxf(rm, __shfl_xor(rm, 4, 16));
      rm = fmaxf(rm, __shfl_xor(rm, 8, 16));
      const float mn = fmaxf(m[r], rm);
      const float alpha = __expf(m[r] - mn);
      m[r] = mn;
      float rs = 0.f;
#pragma unroll
      for (int c = 0; c < 4; ++c) {
        const float p = __expf(s[c][r] - mn);
        s[c][r] = p;
        rs += p;
      }
      rs += __shfl_xor(rs, 1, 16);
      rs += __shfl_xor(rs, 2, 16);
      rs += __shfl_xor(rs, 4, 16);
      rs += __shfl_xor(rs, 8, 16);
      lsum[r] = lsum[r] * alpha + rs;
#pragma unroll
      for (int nt = 0; nt < 4; ++nt) oacc[nt][r] *= alpha;
#pragma unroll
      for (int c = 0; c < 4; ++c) P_lds[w][g * 4 + r][c * 16 + lo] = f2bf(s[c][r]);
    }
    // PV: A-frag = P[q=lane&15][8*(lane>>4)+i + 32*kc], B-frag from vT (contiguous)
#pragma unroll
    for (int kc = 0; kc < 2; ++kc) {
      const bf16x8 aP =
          __builtin_bit_cast(bf16x8, *(const u32x4*)&P_lds[w][lo][kc * 32 + 8 * g]);
#pragma unroll
      for (int nt = 0; nt < 4; ++nt) {
        const bf16x8 bV =
            ld16g(Vh + (size_t)(nt * 16 + lo) * S_SZ + kbase + kc * 32 + 8 * g);
        oacc[nt] = __builtin_amdgcn_mfma_f32_16x16x32_bf16(aP, bV, oacc[nt], 0, 0, 0);
      }
    }
  }
  const int b = bh >> 4, h = bh & 15;
#pragma unroll
  for (int r = 0; r < 4; ++r) {
    const float inv = 1.0f / (lsum[r] + 1e-8f);
    const size_t base = ((size_t)(b * S_SZ + q0 + g * 4 + r)) * 1024 + h * DK;
#pragma unroll
    for (int nt = 0; nt < 4; ++nt) O[base + nt * 16 + lo] = f2bf(oacc[nt][r] * inv);
  }
}

extern "C" void kernel_launch(void* const* d_in, const int* in_sizes, int n_in,
                              void* d_out, int out_size, void* d_ws, size_t ws_size,
                              hipStream_t stream) {
  const float* x = (const float*)d_in[0];      // (2,2048,1024)
  const float* w_qkv = (const float*)d_in[1];  // (3072,1024)
  const float* b_qkv = (const float*)d_in[2];  // (3072)
  const float* w_out = (const float*)d_in[3];  // (1024,1024)
  const float* b_out = (const float*)d_in[4];  // (1024)
  float* out = (float*)d_out;                  // (2,2048,1024) fp32

  char* ws = (char*)d_ws;
  unsigned short* qkv = (unsigned short*)(ws);             // 4096x3072 bf16
  unsigned short* qb = (unsigned short*)(ws + 25165824);   // [B,H,S,64]
  unsigned short* kb = (unsigned short*)(ws + 33554432);   // [B,H,S,64]
  unsigned short* vt = (unsigned short*)(ws + 41943040);   // [B,H,64,S]
  unsigned short* ob = (unsigned short*)(ws + 50331648);   // [B*S,1024]

  {
    dim3 grid(3072 / 128, 4096 / 128);
    gemm_bt<false, true><<<grid, 256, 0, stream>>>(x, w_qkv, b_qkv, qkv, 4096, 3072, 1024);
  }
  rope_scatter<<<(2 * NH * S_SZ * 32) / 256, 256, 0, stream>>>(qkv, qb, kb, vt);
  {
    dim3 grid(S_SZ / 64, 2 * NH);
    flash_attn<<<grid, 256, 0, stream>>>(qb, kb, vt, ob);
  }
  {
    dim3 grid(1024 / 128, 4096 / 128);
    gemm_bt<true, false><<<grid, 256, 0, stream>>>(ob, w_out, b_out, out, 4096, 1024, 1024);
  }
}

// Round 2
// 191.165 us; speedup vs baseline: 1.8021x; 1.8021x over previous
//
#include <hip/hip_runtime.h>

// Round 1: rebuilt flash_attn:
//  - balanced q-block pairing (block j handles q-blocks j and 31-j: 33 units each)
//  - K/V staged to LDS via global_load_lds(16B), double-buffered, XOR-swizzled
//  - Q pre-scaled by 1/8 in rope kernel
// gemm_bt / rope_scatter otherwise as round 0.
// ws layout (bytes): qkv 25165824 | q 8388608 | k 8388608 | vT 8388608 | o 8388608

typedef float f32x4 __attribute__((ext_vector_type(4)));
typedef float fvec4 __attribute__((ext_vector_type(4)));
typedef __bf16 bf16x8 __attribute__((ext_vector_type(8)));
typedef unsigned int u32x4 __attribute__((ext_vector_type(4)));

#define S_SZ 2048
#define NH 16
#define DK 64

static __device__ __forceinline__ unsigned short f2bf(float f) {
  unsigned int u = __builtin_bit_cast(unsigned int, f);
  u += 0x7fffu + ((u >> 16) & 1u);
  return (unsigned short)(u >> 16);
}
static __device__ __forceinline__ float bf2f(unsigned short h) {
  unsigned int u = ((unsigned int)h) << 16;
  return __builtin_bit_cast(float, u);
}
static __device__ __forceinline__ unsigned int pk2(float a, float b) {
  return (unsigned int)f2bf(a) | ((unsigned int)f2bf(b) << 16);
}
static __device__ __forceinline__ bf16x8 ld16g(const unsigned short* p) {
  return __builtin_bit_cast(bf16x8, *(const u32x4*)p);
}
static __device__ __forceinline__ void gload_lds16(const unsigned short* g,
                                                   unsigned short* l) {
  __builtin_amdgcn_global_load_lds(
      (const __attribute__((address_space(1))) void*)g,
      (__attribute__((address_space(3))) void*)l, 16, 0, 0);
}

// ---------------- GEMM (unchanged from round 0) ----------------
template <bool ABF16, bool OBF16>
__global__ __launch_bounds__(256) void gemm_bt(const void* __restrict__ Ap,
                                               const float* __restrict__ Bp,
                                               const float* __restrict__ bias,
                                               void* __restrict__ Cp,
                                               int M, int N, int K) {
  __shared__ unsigned short As[128][40];
  __shared__ unsigned short Bs[128][40];
  const int t = threadIdx.x;
  const int lane = t & 63;
  const int wid = t >> 6;
  const int wr = (wid >> 1) * 64, wc = (wid & 1) * 64;
  const int lo = lane & 15, g = lane >> 4;
  const int bRow = blockIdx.y * 128, bCol = blockIdx.x * 128;
  const int sr = t >> 1, sc = (t & 1) * 16;
  f32x4 acc[4][4] = {};
  for (int k0 = 0; k0 < K; k0 += 32) {
    if constexpr (ABF16) {
      const unsigned short* A16 = (const unsigned short*)Ap;
      const u32x4* ap = (const u32x4*)(A16 + (size_t)(bRow + sr) * K + k0 + sc);
      u32x4 v0 = ap[0], v1 = ap[1];
      *(u32x4*)&As[sr][sc] = v0;
      *(u32x4*)&As[sr][sc + 8] = v1;
    } else {
      const float* Af = (const float*)Ap;
      const fvec4* ap = (const fvec4*)(Af + (size_t)(bRow + sr) * K + k0 + sc);
      fvec4 f0 = ap[0], f1 = ap[1], f2 = ap[2], f3 = ap[3];
      u32x4 u0, u1;
      u0[0] = pk2(f0[0], f0[1]); u0[1] = pk2(f0[2], f0[3]);
      u0[2] = pk2(f1[0], f1[1]); u0[3] = pk2(f1[2], f1[3]);
      u1[0] = pk2(f2[0], f2[1]); u1[1] = pk2(f2[2], f2[3]);
      u1[2] = pk2(f3[0], f3[1]); u1[3] = pk2(f3[2], f3[3]);
      *(u32x4*)&As[sr][sc] = u0;
      *(u32x4*)&As[sr][sc + 8] = u1;
    }
    {
      const fvec4* bp = (const fvec4*)(Bp + (size_t)(bCol + sr) * K + k0 + sc);
      fvec4 f0 = bp[0], f1 = bp[1], f2 = bp[2], f3 = bp[3];
      u32x4 u0, u1;
      u0[0] = pk2(f0[0], f0[1]); u0[1] = pk2(f0[2], f0[3]);
      u0[2] = pk2(f1[0], f1[1]); u0[3] = pk2(f1[2], f1[3]);
      u1[0] = pk2(f2[0], f2[1]); u1[1] = pk2(f2[2], f2[3]);
      u1[2] = pk2(f3[0], f3[1]); u1[3] = pk2(f3[2], f3[3]);
      *(u32x4*)&Bs[sr][sc] = u0;
      *(u32x4*)&Bs[sr][sc + 8] = u1;
    }
    __syncthreads();
    bf16x8 aF[4], bF[4];
#pragma unroll
    for (int m = 0; m < 4; ++m)
      aF[m] = __builtin_bit_cast(bf16x8, *(const u32x4*)&As[wr + m * 16 + lo][8 * g]);
#pragma unroll
    for (int n = 0; n < 4; ++n)
      bF[n] = __builtin_bit_cast(bf16x8, *(const u32x4*)&Bs[wc + n * 16 + lo][8 * g]);
#pragma unroll
    for (int m = 0; m < 4; ++m)
#pragma unroll
      for (int n = 0; n < 4; ++n)
        acc[m][n] = __builtin_amdgcn_mfma_f32_16x16x32_bf16(aF[m], bF[n], acc[m][n], 0, 0, 0);
    __syncthreads();
  }
#pragma unroll
  for (int m = 0; m < 4; ++m) {
#pragma unroll
    for (int n = 0; n < 4; ++n) {
      const int col = bCol + wc + n * 16 + lo;
      const float bv = bias[col];
#pragma unroll
      for (int r = 0; r < 4; ++r) {
        const int row = bRow + wr + m * 16 + g * 4 + r;
        const float v = acc[m][n][r] + bv;
        if constexpr (OBF16)
          ((unsigned short*)Cp)[(size_t)row * N + col] = f2bf(v);
        else
          ((float*)Cp)[(size_t)row * N + col] = v;
      }
    }
  }
}

// ------------- rope + scatter (Q pre-scaled by 1/8) -------------
__global__ __launch_bounds__(256) void rope_scatter(
    const unsigned short* __restrict__ qkv, unsigned short* __restrict__ Qo,
    unsigned short* __restrict__ Ko, unsigned short* __restrict__ Vt) {
  const int t = blockIdx.x * 256 + threadIdx.x;
  const int i = t & 31;
  const int s = (t >> 5) & (S_SZ - 1);
  const int h = (t >> 16) & (NH - 1);
  const int b = t >> 20;
  const unsigned short* row = qkv + (size_t)(b * S_SZ + s) * 3072;
  const float inv = exp2f((float)i * (-13.287712379549449f / 32.0f));
  const float ang = (float)s * inv;
  float sn, cs;
  sincosf(ang, &sn, &cs);
  const unsigned int qp = *(const unsigned int*)(row + h * 64 + 2 * i);
  const unsigned int kp = *(const unsigned int*)(row + 1024 + h * 64 + 2 * i);
  const unsigned int vp = *(const unsigned int*)(row + 2048 + h * 64 + 2 * i);
  const float qe = bf2f((unsigned short)qp), qo = bf2f((unsigned short)(qp >> 16));
  const float ke = bf2f((unsigned short)kp), ko = bf2f((unsigned short)(kp >> 16));
  const size_t hb = (size_t)(b * NH + h);
  const size_t qkbase = (hb * S_SZ + s) * DK + 2 * i;
  *(unsigned int*)(Qo + qkbase) =
      pk2((qe * cs - qo * sn) * 0.125f, (qe * sn + qo * cs) * 0.125f);
  *(unsigned int*)(Ko + qkbase) = pk2(ke * cs - ko * sn, ke * sn + ko * cs);
  const size_t vb = (hb * DK + 2 * i) * S_SZ + s;
  Vt[vb] = (unsigned short)vp;
  Vt[vb + S_SZ] = (unsigned short)(vp >> 16);
}

// ---------------- flash attention v2 ----------------
// Stage a 64x64 bf16 tile (row stride = gstride shorts) into LDS with
// c16 ^= (row&7) swizzle; linear LDS dest, pre-swizzled global source.
static __device__ __forceinline__ void stage_tile(const unsigned short* __restrict__ gbase,
                                                  int gstride, unsigned short* ltile,
                                                  int w, int lane) {
#pragma unroll
  for (int c = 0; c < 2; ++c) {
    const int D = (w * 2048 + c * 1024) + lane * 16;  // dst byte in tile
    const int r = D >> 7;
    const int c16 = (D >> 4) & 7;
    const int s16 = c16 ^ (r & 7);
    gload_lds16(gbase + (size_t)r * gstride + (s16 << 3),
                ltile + (w * 1024 + c * 512));  // wave-uniform base (shorts)
  }
}

// One 16-q-row x 64-key step for one wave, K/V from swizzled LDS tiles.
static __device__ __forceinline__ void attn_step(
    const unsigned short* __restrict__ Kl, const unsigned short* __restrict__ Vl,
    unsigned short* __restrict__ Pw, const bf16x8 aQ0, const bf16x8 aQ1,
    const bool diag, const int w, const int lo, const int g,
    float* __restrict__ m, float* __restrict__ lsum, f32x4* __restrict__ oacc) {
  f32x4 s[4];
#pragma unroll
  for (int c = 0; c < 4; ++c) {
    const int kr = c * 16 + lo;
    const int sw = kr & 7;
    const bf16x8 b0 =
        __builtin_bit_cast(bf16x8, *(const u32x4*)&Kl[kr * 64 + ((g ^ sw) << 3)]);
    const bf16x8 b1 =
        __builtin_bit_cast(bf16x8, *(const u32x4*)&Kl[kr * 64 + (((4 + g) ^ sw) << 3)]);
    f32x4 z = {};
    z = __builtin_amdgcn_mfma_f32_16x16x32_bf16(aQ0, b0, z, 0, 0, 0);
    z = __builtin_amdgcn_mfma_f32_16x16x32_bf16(aQ1, b1, z, 0, 0, 0);
    s[c] = z;
  }
  if (diag) {
#pragma unroll
    for (int c = 0; c < 4; ++c)
#pragma unroll
      for (int r = 0; r < 4; ++r)
        if ((c * 16 + lo) > (w * 16 + g * 4 + r)) s[c][r] = -__builtin_inff();
  }
#pragma unroll
  for (int r = 0; r < 4; ++r) {
    float rm = fmaxf(fmaxf(s[0][r], s[1][r]), fmaxf(s[2][r], s[3][r]));
    rm = fmaxf(rm, __shfl_xor(rm, 1, 16));
    rm = fmaxf(rm, __shfl_xor(rm, 2, 16));
    rm = fmaxf(rm, __shfl_xor(rm, 4, 16));
    rm = fmaxf(rm, __shfl_xor(rm, 8, 16));
    const float mn = fmaxf(m[r], rm);
    const float alpha = __expf(m[r] - mn);
    m[r] = mn;
    float rs = 0.f;
#pragma unroll
    for (int c = 0; c < 4; ++c) {
      const float p = __expf(s[c][r] - mn);
      s[c][r] = p;
      rs += p;
    }
    rs += __shfl_xor(rs, 1, 16);
    rs += __shfl_xor(rs, 2, 16);
    rs += __shfl_xor(rs, 4, 16);
    rs += __shfl_xor(rs, 8, 16);
    lsum[r] = lsum[r] * alpha + rs;
#pragma unroll
    for (int nt = 0; nt < 4; ++nt) oacc[nt][r] *= alpha;
#pragma unroll
    for (int c = 0; c < 4; ++c) Pw[(g * 4 + r) * 72 + c * 16 + lo] = f2bf(s[c][r]);
  }
#pragma unroll
  for (int kc = 0; kc < 2; ++kc) {
    const bf16x8 aP =
        __builtin_bit_cast(bf16x8, *(const u32x4*)&Pw[lo * 72 + kc * 32 + 8 * g]);
#pragma unroll
    for (int nt = 0; nt < 4; ++nt) {
      const int d = nt * 16 + lo;
      const bf16x8 bV = __builtin_bit_cast(
          bf16x8, *(const u32x4*)&Vl[d * 64 + (((kc * 4 + g) ^ (d & 7)) << 3)]);
      oacc[nt] = __builtin_amdgcn_mfma_f32_16x16x32_bf16(aP, bV, oacc[nt], 0, 0, 0);
    }
  }
}

__global__ __launch_bounds__(256) void flash_attn(
    const unsigned short* __restrict__ Q, const unsigned short* __restrict__ K,
    const unsigned short* __restrict__ VT, unsigned short* __restrict__ O) {
  __shared__ unsigned short Kb[2][4096];
  __shared__ unsigned short Vb[2][4096];
  __shared__ unsigned short Pl[4][16 * 72];
  const int t = threadIdx.x;
  const int lane = t & 63, w = t >> 6;
  const int lo = lane & 15, g = lane >> 4;
  const int bh = blockIdx.y;        // b*16 + h
  const int j = blockIdx.x;         // 0..15 -> q-block pair (j, 31-j)
  const int qa = j, qb = 31 - j;
  const unsigned short* Qh = Q + (size_t)bh * S_SZ * DK;
  const unsigned short* Kh = K + (size_t)bh * S_SZ * DK;
  const unsigned short* Vh = VT + (size_t)bh * DK * S_SZ;

  const int rowA = qa * 64 + w * 16, rowB = qb * 64 + w * 16;
  const bf16x8 aQA0 = ld16g(Qh + (size_t)(rowA + lo) * DK + 8 * g);
  const bf16x8 aQA1 = ld16g(Qh + (size_t)(rowA + lo) * DK + 32 + 8 * g);
  const bf16x8 aQB0 = ld16g(Qh + (size_t)(rowB + lo) * DK + 8 * g);
  const bf16x8 aQB1 = ld16g(Qh + (size_t)(rowB + lo) * DK + 32 + 8 * g);

  float mA[4], lA[4], mB[4], lB[4];
  f32x4 oA[4] = {}, oB[4] = {};
#pragma unroll
  for (int r = 0; r < 4; ++r) {
    mA[r] = mB[r] = -__builtin_inff();
    lA[r] = lB[r] = 0.f;
  }
  unsigned short* Pw = &Pl[w][0];

  // prologue: stage tile 0
  stage_tile(Kh, DK, Kb[0], w, lane);
  stage_tile(Vh, S_SZ, Vb[0], w, lane);
  __syncthreads();
  int cur = 0;
  for (int kt = 0; kt <= qb; ++kt) {
    if (kt < qb) {
      const int nb = (kt + 1) * 64;
      stage_tile(Kh + (size_t)nb * DK, DK, Kb[cur ^ 1], w, lane);
      stage_tile(Vh + nb, S_SZ, Vb[cur ^ 1], w, lane);
    }
    attn_step(Kb[cur], Vb[cur], Pw, aQB0, aQB1, kt == qb, w, lo, g, mB, lB, oB);
    if (kt <= qa)
      attn_step(Kb[cur], Vb[cur], Pw, aQA0, aQA1, kt == qa, w, lo, g, mA, lA, oA);
    __syncthreads();  // drains vmcnt (staging) + lgkmcnt before buffer swap
    cur ^= 1;
  }

  const int b = bh >> 4, h = bh & 15;
#pragma unroll
  for (int r = 0; r < 4; ++r) {
    const float invB = 1.0f / (lB[r] + 1e-8f);
    const size_t baseB = ((size_t)(b * S_SZ + rowB + g * 4 + r)) * 1024 + h * DK;
#pragma unroll
    for (int nt = 0; nt < 4; ++nt) O[baseB + nt * 16 + lo] = f2bf(oB[nt][r] * invB);
    const float invA = 1.0f / (lA[r] + 1e-8f);
    const size_t baseA = ((size_t)(b * S_SZ + rowA + g * 4 + r)) * 1024 + h * DK;
#pragma unroll
    for (int nt = 0; nt < 4; ++nt) O[baseA + nt * 16 + lo] = f2bf(oA[nt][r] * invA);
  }
}

extern "C" void kernel_launch(void* const* d_in, const int* in_sizes, int n_in,
                              void* d_out, int out_size, void* d_ws, size_t ws_size,
                              hipStream_t stream) {
  const float* x = (const float*)d_in[0];
  const float* w_qkv = (const float*)d_in[1];
  const float* b_qkv = (const float*)d_in[2];
  const float* w_out = (const float*)d_in[3];
  const float* b_out = (const float*)d_in[4];
  float* out = (float*)d_out;

  char* ws = (char*)d_ws;
  unsigned short* qkv = (unsigned short*)(ws);
  unsigned short* qb = (unsigned short*)(ws + 25165824);
  unsigned short* kb = (unsigned short*)(ws + 33554432);
  unsigned short* vt = (unsigned short*)(ws + 41943040);
  unsigned short* ob = (unsigned short*)(ws + 50331648);

  {
    dim3 grid(3072 / 128, 4096 / 128);
    gemm_bt<false, true><<<grid, 256, 0, stream>>>(x, w_qkv, b_qkv, qkv, 4096, 3072, 1024);
  }
  rope_scatter<<<(2 * NH * S_SZ * 32) / 256, 256, 0, stream>>>(qkv, qb, kb, vt);
  {
    dim3 grid(16, 2 * NH);
    flash_attn<<<grid, 256, 0, stream>>>(qb, kb, vt, ob);
  }
  {
    dim3 grid(1024 / 128, 4096 / 128);
    gemm_bt<true, false><<<grid, 256, 0, stream>>>(ob, w_out, b_out, out, 4096, 1024, 1024);
  }
}

// Round 3
// 152.949 us; speedup vs baseline: 2.2524x; 1.2499x over previous
//
#include <hip/hip_runtime.h>

// Round 2:
//  - cvt_bf16: pre-convert x, w_qkv, w_out to bf16 (one pass)
//  - gemm_bf16: m97-style pure-bf16 GEMM (global_load_lds x16, LDS dbuf,
//    stage-next-before-compute, 1 barrier/K-step)
//  - flash_attn: 512 threads / 8 waves; waves 0-3 -> q-block j, waves 4-7 ->
//    q-block 31-j; shared K/V staging; setprio around MFMA
// ws layout (bytes), 56 MB total with aliasing:
//   0        xb (8388608)            -> reused as qb after gemm1
//   8388608  wqb (6291456)
//   14680064 wob (2097152)
//   16777216 qkv (25165824)          -> first 8 MB reused as ob after rope
//   41943040 kb (8388608)
//   50331648 vT (8388608)

typedef float f32x4 __attribute__((ext_vector_type(4)));
typedef float fvec4 __attribute__((ext_vector_type(4)));
typedef __bf16 bf16x8 __attribute__((ext_vector_type(8)));
typedef unsigned int u32x4 __attribute__((ext_vector_type(4)));

#define S_SZ 2048
#define NH 16
#define DK 64

static __device__ __forceinline__ unsigned short f2bf(float f) {
  unsigned int u = __builtin_bit_cast(unsigned int, f);
  u += 0x7fffu + ((u >> 16) & 1u);
  return (unsigned short)(u >> 16);
}
static __device__ __forceinline__ float bf2f(unsigned short h) {
  unsigned int u = ((unsigned int)h) << 16;
  return __builtin_bit_cast(float, u);
}
static __device__ __forceinline__ unsigned int pk2(float a, float b) {
  return (unsigned int)f2bf(a) | ((unsigned int)f2bf(b) << 16);
}
static __device__ __forceinline__ bf16x8 ld16g(const unsigned short* p) {
  return __builtin_bit_cast(bf16x8, *(const u32x4*)p);
}
static __device__ __forceinline__ void gload_lds16(const unsigned short* g,
                                                   unsigned short* l) {
  __builtin_amdgcn_global_load_lds(
      (const __attribute__((address_space(1))) void*)g,
      (__attribute__((address_space(3))) void*)l, 16, 0, 0);
}

// ---------------- convert fp32 -> bf16 (x, w_qkv, w_out) ----------------
__global__ __launch_bounds__(256) void cvt_bf16(
    const float* __restrict__ x, const float* __restrict__ wq,
    const float* __restrict__ wo, unsigned short* __restrict__ xb,
    unsigned short* __restrict__ wqb, unsigned short* __restrict__ wob) {
  const int u = blockIdx.x * 256 + threadIdx.x;  // 1048576 threads, 8 elems each
  const float* src;
  unsigned short* dst;
  int idx;
  if (u < 524288) { src = x; dst = xb; idx = u; }
  else if (u < 917504) { src = wq; dst = wqb; idx = u - 524288; }
  else { src = wo; dst = wob; idx = u - 917504; }
  const fvec4* p = (const fvec4*)(src + (size_t)idx * 8);
  const fvec4 f0 = p[0], f1 = p[1];
  u32x4 o;
  o[0] = pk2(f0[0], f0[1]); o[1] = pk2(f0[2], f0[3]);
  o[2] = pk2(f1[0], f1[1]); o[3] = pk2(f1[2], f1[3]);
  *(u32x4*)(dst + (size_t)idx * 8) = o;
}

// ---------------- m97-style bf16 GEMM ----------------
// C[m][n] = sum_k A[m][k]*B[n][k] + bias[n]; A (M,K) bf16, B (N,K) bf16.
// 128x128 tile, BK=32, LDS double-buffer, global_load_lds(16B).
template <bool OBF16>
__global__ __launch_bounds__(256) void gemm_bf16(
    const unsigned short* __restrict__ A, const unsigned short* __restrict__ B,
    const float* __restrict__ bias, void* __restrict__ Cp, int N, int K) {
  __shared__ unsigned short As[2][4096];
  __shared__ unsigned short Bs[2][4096];
  const int t = threadIdx.x;
  const int lane = t & 63, w = t >> 6;
  const int lo = lane & 15, g = lane >> 4;
  const int wr = (w >> 1) * 64, wc = (w & 1) * 64;
  const int bRow = blockIdx.y * 128, bCol = blockIdx.x * 128;
  const unsigned short* ap = A + (size_t)(bRow + (t >> 2)) * K + (t & 3) * 8;
  const unsigned short* bp = B + (size_t)(bCol + (t >> 2)) * K + (t & 3) * 8;
  const size_t rK = (size_t)64 * K;
  const int wb = w * 512;  // wave LDS base (shorts)
  f32x4 acc[4][4] = {};
  // prologue: stage tile 0 into buf 0
  gload_lds16(ap, As[0] + wb);
  gload_lds16(ap + rK, As[0] + 2048 + wb);
  gload_lds16(bp, Bs[0] + wb);
  gload_lds16(bp + rK, Bs[0] + 2048 + wb);
  const int nk = K >> 5;
  for (int kt = 0; kt < nk; ++kt) {
    __syncthreads();  // drains staging of buf[kt&1]
    if (kt + 1 < nk) {
      const int k0 = (kt + 1) << 5;
      const int nb = (kt + 1) & 1;
      gload_lds16(ap + k0, As[nb] + wb);
      gload_lds16(ap + rK + k0, As[nb] + 2048 + wb);
      gload_lds16(bp + k0, Bs[nb] + wb);
      gload_lds16(bp + rK + k0, Bs[nb] + 2048 + wb);
    }
    const unsigned short* Ac = As[kt & 1];
    const unsigned short* Bc = Bs[kt & 1];
    bf16x8 aF[4], bF[4];
#pragma unroll
    for (int m = 0; m < 4; ++m) aF[m] = ld16g(Ac + (wr + m * 16 + lo) * 32 + 8 * g);
#pragma unroll
    for (int n = 0; n < 4; ++n) bF[n] = ld16g(Bc + (wc + n * 16 + lo) * 32 + 8 * g);
    __builtin_amdgcn_s_setprio(1);
#pragma unroll
    for (int m = 0; m < 4; ++m)
#pragma unroll
      for (int n = 0; n < 4; ++n)
        acc[m][n] = __builtin_amdgcn_mfma_f32_16x16x32_bf16(aF[m], bF[n], acc[m][n], 0, 0, 0);
    __builtin_amdgcn_s_setprio(0);
  }
#pragma unroll
  for (int m = 0; m < 4; ++m) {
#pragma unroll
    for (int n = 0; n < 4; ++n) {
      const int col = bCol + wc + n * 16 + lo;
      const float bv = bias[col];
#pragma unroll
      for (int r = 0; r < 4; ++r) {
        const int row = bRow + wr + m * 16 + g * 4 + r;
        const float v = acc[m][n][r] + bv;
        if constexpr (OBF16)
          ((unsigned short*)Cp)[(size_t)row * N + col] = f2bf(v);
        else
          ((float*)Cp)[(size_t)row * N + col] = v;
      }
    }
  }
}

// ------------- rope + scatter (Q pre-scaled by 1/8) -------------
__global__ __launch_bounds__(256) void rope_scatter(
    const unsigned short* __restrict__ qkv, unsigned short* __restrict__ Qo,
    unsigned short* __restrict__ Ko, unsigned short* __restrict__ Vt) {
  const int t = blockIdx.x * 256 + threadIdx.x;
  const int i = t & 31;
  const int s = (t >> 5) & (S_SZ - 1);
  const int h = (t >> 16) & (NH - 1);
  const int b = t >> 20;
  const unsigned short* row = qkv + (size_t)(b * S_SZ + s) * 3072;
  const float inv = exp2f((float)i * (-13.287712379549449f / 32.0f));
  const float ang = (float)s * inv;
  float sn, cs;
  sincosf(ang, &sn, &cs);
  const unsigned int qp = *(const unsigned int*)(row + h * 64 + 2 * i);
  const unsigned int kp = *(const unsigned int*)(row + 1024 + h * 64 + 2 * i);
  const unsigned int vp = *(const unsigned int*)(row + 2048 + h * 64 + 2 * i);
  const float qe = bf2f((unsigned short)qp), qo = bf2f((unsigned short)(qp >> 16));
  const float ke = bf2f((unsigned short)kp), ko = bf2f((unsigned short)(kp >> 16));
  const size_t hb = (size_t)(b * NH + h);
  const size_t qkbase = (hb * S_SZ + s) * DK + 2 * i;
  *(unsigned int*)(Qo + qkbase) =
      pk2((qe * cs - qo * sn) * 0.125f, (qe * sn + qo * cs) * 0.125f);
  *(unsigned int*)(Ko + qkbase) = pk2(ke * cs - ko * sn, ke * sn + ko * cs);
  const size_t vb = (hb * DK + 2 * i) * S_SZ + s;
  Vt[vb] = (unsigned short)vp;
  Vt[vb + S_SZ] = (unsigned short)(vp >> 16);
}

// ---------------- flash attention v3 (8 waves) ----------------
// Stage 64x64 bf16 tile, 512 threads, 1 issue each; swizzle c16 ^= row&7.
static __device__ __forceinline__ void stage8(const unsigned short* __restrict__ gbase,
                                              int gstride, unsigned short* tile, int t) {
  const int r = t >> 3;
  const int s16 = (t & 7) ^ (r & 7);
  gload_lds16(gbase + (size_t)r * gstride + (s16 << 3), tile + (t >> 6) * 512);
}

static __device__ __forceinline__ void attn_step(
    const unsigned short* __restrict__ Kl, const unsigned short* __restrict__ Vl,
    unsigned short* __restrict__ Pw, const bf16x8 aQ0, const bf16x8 aQ1,
    const bool diag, const int wq, const int lo, const int g,
    float* __restrict__ m, float* __restrict__ lsum, f32x4* __restrict__ oacc) {
  f32x4 s[4];
  __builtin_amdgcn_s_setprio(1);
#pragma unroll
  for (int c = 0; c < 4; ++c) {
    const int kr = c * 16 + lo;
    const int sw = kr & 7;
    const bf16x8 b0 =
        __builtin_bit_cast(bf16x8, *(const u32x4*)&Kl[kr * 64 + ((g ^ sw) << 3)]);
    const bf16x8 b1 =
        __builtin_bit_cast(bf16x8, *(const u32x4*)&Kl[kr * 64 + (((4 + g) ^ sw) << 3)]);
    f32x4 z = {};
    z = __builtin_amdgcn_mfma_f32_16x16x32_bf16(aQ0, b0, z, 0, 0, 0);
    z = __builtin_amdgcn_mfma_f32_16x16x32_bf16(aQ1, b1, z, 0, 0, 0);
    s[c] = z;
  }
  __builtin_amdgcn_s_setprio(0);
  if (diag) {
#pragma unroll
    for (int c = 0; c < 4; ++c)
#pragma unroll
      for (int r = 0; r < 4; ++r)
        if ((c * 16 + lo) > (wq * 16 + g * 4 + r)) s[c][r] = -__builtin_inff();
  }
#pragma unroll
  for (int r = 0; r < 4; ++r) {
    float rm = fmaxf(fmaxf(s[0][r], s[1][r]), fmaxf(s[2][r], s[3][r]));
    rm = fmaxf(rm, __shfl_xor(rm, 1, 16));
    rm = fmaxf(rm, __shfl_xor(rm, 2, 16));
    rm = fmaxf(rm, __shfl_xor(rm, 4, 16));
    rm = fmaxf(rm, __shfl_xor(rm, 8, 16));
    const float mn = fmaxf(m[r], rm);
    const float alpha = __expf(m[r] - mn);
    m[r] = mn;
    float rs = 0.f;
#pragma unroll
    for (int c = 0; c < 4; ++c) {
      const float p = __expf(s[c][r] - mn);
      s[c][r] = p;
      rs += p;
    }
    rs += __shfl_xor(rs, 1, 16);
    rs += __shfl_xor(rs, 2, 16);
    rs += __shfl_xor(rs, 4, 16);
    rs += __shfl_xor(rs, 8, 16);
    lsum[r] = lsum[r] * alpha + rs;
#pragma unroll
    for (int nt = 0; nt < 4; ++nt) oacc[nt][r] *= alpha;
#pragma unroll
    for (int c = 0; c < 4; ++c) Pw[(g * 4 + r) * 72 + c * 16 + lo] = f2bf(s[c][r]);
  }
  __builtin_amdgcn_s_setprio(1);
#pragma unroll
  for (int kc = 0; kc < 2; ++kc) {
    const bf16x8 aP =
        __builtin_bit_cast(bf16x8, *(const u32x4*)&Pw[lo * 72 + kc * 32 + 8 * g]);
#pragma unroll
    for (int nt = 0; nt < 4; ++nt) {
      const int d = nt * 16 + lo;
      const bf16x8 bV = __builtin_bit_cast(
          bf16x8, *(const u32x4*)&Vl[d * 64 + (((kc * 4 + g) ^ (d & 7)) << 3)]);
      oacc[nt] = __builtin_amdgcn_mfma_f32_16x16x32_bf16(aP, bV, oacc[nt], 0, 0, 0);
    }
  }
  __builtin_amdgcn_s_setprio(0);
}

__global__ __launch_bounds__(512) void flash_attn(
    const unsigned short* __restrict__ Q, const unsigned short* __restrict__ K,
    const unsigned short* __restrict__ VT, unsigned short* __restrict__ O) {
  __shared__ unsigned short Kb[2][4096];
  __shared__ unsigned short Vb[2][4096];
  __shared__ unsigned short Pl[8][16 * 72];
  const int t = threadIdx.x;
  const int lane = t & 63, w = t >> 6;  // w 0..7
  const int lo = lane & 15, g = lane >> 4;
  const int bh = blockIdx.y;  // b*16 + h
  const int j = blockIdx.x;   // pair (j, 31-j)
  const int qa = j, qb = 31 - j;
  const unsigned short* Qh = Q + (size_t)bh * S_SZ * DK;
  const unsigned short* Kh = K + (size_t)bh * S_SZ * DK;
  const unsigned short* Vh = VT + (size_t)bh * DK * S_SZ;

  const int wq = w & 3;
  const int myq = (w & 4) ? qb : qa;
  const int row = myq * 64 + wq * 16;
  const bf16x8 aQ0 = ld16g(Qh + (size_t)(row + lo) * DK + 8 * g);
  const bf16x8 aQ1 = ld16g(Qh + (size_t)(row + lo) * DK + 32 + 8 * g);

  float m[4], l[4];
  f32x4 o[4] = {};
#pragma unroll
  for (int r = 0; r < 4; ++r) { m[r] = -__builtin_inff(); l[r] = 0.f; }
  unsigned short* Pw = &Pl[w][0];

  stage8(Kh, DK, Kb[0], t);
  stage8(Vh, S_SZ, Vb[0], t);
  __syncthreads();
  int cur = 0;
  for (int kt = 0; kt <= qb; ++kt) {
    if (kt < qb) {
      const int nb = (kt + 1) * 64;
      stage8(Kh + (size_t)nb * DK, DK, Kb[cur ^ 1], t);
      stage8(Vh + nb, S_SZ, Vb[cur ^ 1], t);
    }
    if (kt <= myq)
      attn_step(Kb[cur], Vb[cur], Pw, aQ0, aQ1, kt == myq, wq, lo, g, m, l, o);
    __syncthreads();
    cur ^= 1;
  }

  const int b = bh >> 4, h = bh & 15;
#pragma unroll
  for (int r = 0; r < 4; ++r) {
    const float inv = 1.0f / (l[r] + 1e-8f);
    const size_t base = ((size_t)(b * S_SZ + row + g * 4 + r)) * 1024 + h * DK;
#pragma unroll
    for (int nt = 0; nt < 4; ++nt) O[base + nt * 16 + lo] = f2bf(o[nt][r] * inv);
  }
}

extern "C" void kernel_launch(void* const* d_in, const int* in_sizes, int n_in,
                              void* d_out, int out_size, void* d_ws, size_t ws_size,
                              hipStream_t stream) {
  const float* x = (const float*)d_in[0];
  const float* w_qkv = (const float*)d_in[1];
  const float* b_qkv = (const float*)d_in[2];
  const float* w_out = (const float*)d_in[3];
  const float* b_out = (const float*)d_in[4];
  float* out = (float*)d_out;

  char* ws = (char*)d_ws;
  unsigned short* xb = (unsigned short*)(ws);              // 8 MB; reused as qb
  unsigned short* wqb = (unsigned short*)(ws + 8388608);   // 6 MB
  unsigned short* wob = (unsigned short*)(ws + 14680064);  // 2 MB
  unsigned short* qkv = (unsigned short*)(ws + 16777216);  // 24 MB; head reused as ob
  unsigned short* kb = (unsigned short*)(ws + 41943040);   // 8 MB
  unsigned short* vt = (unsigned short*)(ws + 50331648);   // 8 MB
  unsigned short* qb = xb;
  unsigned short* ob = qkv;

  cvt_bf16<<<4096, 256, 0, stream>>>(x, w_qkv, w_out, xb, wqb, wob);
  {
    dim3 grid(3072 / 128, 4096 / 128);
    gemm_bf16<true><<<grid, 256, 0, stream>>>(xb, wqb, b_qkv, qkv, 3072, 1024);
  }
  rope_scatter<<<(2 * NH * S_SZ * 32) / 256, 256, 0, stream>>>(qkv, qb, kb, vt);
  {
    dim3 grid(16, 2 * NH);
    flash_attn<<<grid, 512, 0, stream>>>(qb, kb, vt, ob);
  }
  {
    dim3 grid(1024 / 128, 4096 / 128);
    gemm_bf16<false><<<grid, 256, 0, stream>>>(ob, wob, b_out, out, 1024, 1024);
  }
}

// Round 4
// 135.544 us; speedup vs baseline: 2.5416x; 1.1284x over previous
//
#include <hip/hip_runtime.h>

// Round 3:
//  - flash_attn: balanced work-stealing split: waves 4-7 do K-tiles 0..15 of
//    q-block qb; waves 0-3 do q-block qa fully then K-tiles 16..qb of qb
//    (17 vs 16 steps for EVERY block); end merge of (m,l,o) partials via LDS.
//  - softmax reductions via DPP butterflies (VALU) instead of shfl/ds_swizzle.
//  - GEMMs: bijective XCD-aware block swizzle (grids 768/256, both %8==0).
// ws layout (bytes):
//   0        xb (8388608)            -> reused as qb after gemm1
//   8388608  wqb (6291456)
//   14680064 wob (2097152)
//   16777216 qkv (25165824)          -> first 8 MB reused as ob after rope
//   41943040 kb (8388608)
//   50331648 vT (8388608)

typedef float f32x4 __attribute__((ext_vector_type(4)));
typedef float fvec4 __attribute__((ext_vector_type(4)));
typedef __bf16 bf16x8 __attribute__((ext_vector_type(8)));
typedef unsigned int u32x4 __attribute__((ext_vector_type(4)));

#define S_SZ 2048
#define NH 16
#define DK 64

static __device__ __forceinline__ unsigned short f2bf(float f) {
  unsigned int u = __builtin_bit_cast(unsigned int, f);
  u += 0x7fffu + ((u >> 16) & 1u);
  return (unsigned short)(u >> 16);
}
static __device__ __forceinline__ float bf2f(unsigned short h) {
  unsigned int u = ((unsigned int)h) << 16;
  return __builtin_bit_cast(float, u);
}
static __device__ __forceinline__ unsigned int pk2(float a, float b) {
  return (unsigned int)f2bf(a) | ((unsigned int)f2bf(b) << 16);
}
static __device__ __forceinline__ bf16x8 ld16g(const unsigned short* p) {
  return __builtin_bit_cast(bf16x8, *(const u32x4*)p);
}
static __device__ __forceinline__ void gload_lds16(const unsigned short* g,
                                                   unsigned short* l) {
  __builtin_amdgcn_global_load_lds(
      (const __attribute__((address_space(1))) void*)g,
      (__attribute__((address_space(3))) void*)l, 16, 0, 0);
}

// DPP lane-permute move within 16-lane rows (VALU, no LDS pipe).
template <int CTRL>
static __device__ __forceinline__ float dppmov(float x) {
  return __builtin_bit_cast(
      float, __builtin_amdgcn_update_dpp(0, __builtin_bit_cast(int, x), CTRL,
                                         0xF, 0xF, true));
}
// Butterfly reduce over each 16-lane group: xor1, xor2, i^7, i^15.
static __device__ __forceinline__ float rmax16(float x) {
  x = fmaxf(x, dppmov<0xB1>(x));   // quad_perm(1,0,3,2)
  x = fmaxf(x, dppmov<0x4E>(x));   // quad_perm(2,3,0,1)
  x = fmaxf(x, dppmov<0x141>(x));  // row_half_mirror
  x = fmaxf(x, dppmov<0x140>(x));  // row_mirror
  return x;
}
static __device__ __forceinline__ float rsum16(float x) {
  x += dppmov<0xB1>(x);
  x += dppmov<0x4E>(x);
  x += dppmov<0x141>(x);
  x += dppmov<0x140>(x);
  return x;
}

// ---------------- convert fp32 -> bf16 (x, w_qkv, w_out) ----------------
__global__ __launch_bounds__(256) void cvt_bf16(
    const float* __restrict__ x, const float* __restrict__ wq,
    const float* __restrict__ wo, unsigned short* __restrict__ xb,
    unsigned short* __restrict__ wqb, unsigned short* __restrict__ wob) {
  const int u = blockIdx.x * 256 + threadIdx.x;
  const float* src;
  unsigned short* dst;
  int idx;
  if (u < 524288) { src = x; dst = xb; idx = u; }
  else if (u < 917504) { src = wq; dst = wqb; idx = u - 524288; }
  else { src = wo; dst = wob; idx = u - 917504; }
  const fvec4* p = (const fvec4*)(src + (size_t)idx * 8);
  const fvec4 f0 = p[0], f1 = p[1];
  u32x4 o;
  o[0] = pk2(f0[0], f0[1]); o[1] = pk2(f0[2], f0[3]);
  o[2] = pk2(f1[0], f1[1]); o[3] = pk2(f1[2], f1[3]);
  *(u32x4*)(dst + (size_t)idx * 8) = o;
}

// ---------------- m97-style bf16 GEMM + XCD swizzle ----------------
template <bool OBF16>
__global__ __launch_bounds__(256) void gemm_bf16(
    const unsigned short* __restrict__ A, const unsigned short* __restrict__ B,
    const float* __restrict__ bias, void* __restrict__ Cp, int N, int K) {
  __shared__ unsigned short As[2][4096];
  __shared__ unsigned short Bs[2][4096];
  const int t = threadIdx.x;
  const int lane = t & 63, w = t >> 6;
  const int lo = lane & 15, g = lane >> 4;
  const int wr = (w >> 1) * 64, wc = (w & 1) * 64;
  // bijective XCD swizzle (nwg % 8 == 0 for both launches)
  const int gx = gridDim.x;
  int o = blockIdx.y * gx + blockIdx.x;
  const int nwg = gx * gridDim.y;
  o = (o & 7) * (nwg >> 3) + (o >> 3);
  const int by = o / gx, bx = o - by * gx;
  const int bRow = by * 128, bCol = bx * 128;
  const unsigned short* ap = A + (size_t)(bRow + (t >> 2)) * K + (t & 3) * 8;
  const unsigned short* bp = B + (size_t)(bCol + (t >> 2)) * K + (t & 3) * 8;
  const size_t rK = (size_t)64 * K;
  const int wb = w * 512;
  f32x4 acc[4][4] = {};
  gload_lds16(ap, As[0] + wb);
  gload_lds16(ap + rK, As[0] + 2048 + wb);
  gload_lds16(bp, Bs[0] + wb);
  gload_lds16(bp + rK, Bs[0] + 2048 + wb);
  const int nk = K >> 5;
  for (int kt = 0; kt < nk; ++kt) {
    __syncthreads();
    if (kt + 1 < nk) {
      const int k0 = (kt + 1) << 5;
      const int nb = (kt + 1) & 1;
      gload_lds16(ap + k0, As[nb] + wb);
      gload_lds16(ap + rK + k0, As[nb] + 2048 + wb);
      gload_lds16(bp + k0, Bs[nb] + wb);
      gload_lds16(bp + rK + k0, Bs[nb] + 2048 + wb);
    }
    const unsigned short* Ac = As[kt & 1];
    const unsigned short* Bc = Bs[kt & 1];
    bf16x8 aF[4], bF[4];
#pragma unroll
    for (int m = 0; m < 4; ++m) aF[m] = ld16g(Ac + (wr + m * 16 + lo) * 32 + 8 * g);
#pragma unroll
    for (int n = 0; n < 4; ++n) bF[n] = ld16g(Bc + (wc + n * 16 + lo) * 32 + 8 * g);
    __builtin_amdgcn_s_setprio(1);
#pragma unroll
    for (int m = 0; m < 4; ++m)
#pragma unroll
      for (int n = 0; n < 4; ++n)
        acc[m][n] = __builtin_amdgcn_mfma_f32_16x16x32_bf16(aF[m], bF[n], acc[m][n], 0, 0, 0);
    __builtin_amdgcn_s_setprio(0);
  }
#pragma unroll
  for (int m = 0; m < 4; ++m) {
#pragma unroll
    for (int n = 0; n < 4; ++n) {
      const int col = bCol + wc + n * 16 + lo;
      const float bv = bias[col];
#pragma unroll
      for (int r = 0; r < 4; ++r) {
        const int row = bRow + wr + m * 16 + g * 4 + r;
        const float v = acc[m][n][r] + bv;
        if constexpr (OBF16)
          ((unsigned short*)Cp)[(size_t)row * N + col] = f2bf(v);
        else
          ((float*)Cp)[(size_t)row * N + col] = v;
      }
    }
  }
}

// ------------- rope + scatter (Q pre-scaled by 1/8) -------------
__global__ __launch_bounds__(256) void rope_scatter(
    const unsigned short* __restrict__ qkv, unsigned short* __restrict__ Qo,
    unsigned short* __restrict__ Ko, unsigned short* __restrict__ Vt) {
  const int t = blockIdx.x * 256 + threadIdx.x;
  const int i = t & 31;
  const int s = (t >> 5) & (S_SZ - 1);
  const int h = (t >> 16) & (NH - 1);
  const int b = t >> 20;
  const unsigned short* row = qkv + (size_t)(b * S_SZ + s) * 3072;
  const float inv = exp2f((float)i * (-13.287712379549449f / 32.0f));
  const float ang = (float)s * inv;
  float sn, cs;
  sincosf(ang, &sn, &cs);
  const unsigned int qp = *(const unsigned int*)(row + h * 64 + 2 * i);
  const unsigned int kp = *(const unsigned int*)(row + 1024 + h * 64 + 2 * i);
  const unsigned int vp = *(const unsigned int*)(row + 2048 + h * 64 + 2 * i);
  const float qe = bf2f((unsigned short)qp), qo = bf2f((unsigned short)(qp >> 16));
  const float ke = bf2f((unsigned short)kp), ko = bf2f((unsigned short)(kp >> 16));
  const size_t hb = (size_t)(b * NH + h);
  const size_t qkbase = (hb * S_SZ + s) * DK + 2 * i;
  *(unsigned int*)(Qo + qkbase) =
      pk2((qe * cs - qo * sn) * 0.125f, (qe * sn + qo * cs) * 0.125f);
  *(unsigned int*)(Ko + qkbase) = pk2(ke * cs - ko * sn, ke * sn + ko * cs);
  const size_t vb = (hb * DK + 2 * i) * S_SZ + s;
  Vt[vb] = (unsigned short)vp;
  Vt[vb + S_SZ] = (unsigned short)(vp >> 16);
}

// ---------------- flash attention v4 ----------------
// Stage 64x64 bf16 tile with 512 threads; swizzle c16 ^= row&7.
static __device__ __forceinline__ void stage8(const unsigned short* __restrict__ gbase,
                                              int gstride, unsigned short* tile, int t) {
  const int r = t >> 3;
  const int s16 = (t & 7) ^ (r & 7);
  gload_lds16(gbase + (size_t)r * gstride + (s16 << 3), tile + (t >> 6) * 512);
}

static __device__ __forceinline__ void attn_step(
    const unsigned short* __restrict__ Kl, const unsigned short* __restrict__ Vl,
    unsigned short* __restrict__ Pw, const bf16x8 aQ0, const bf16x8 aQ1,
    const bool diag, const int wq, const int lo, const int g,
    float* __restrict__ m, float* __restrict__ lsum, f32x4* __restrict__ oacc) {
  f32x4 s[4];
  __builtin_amdgcn_s_setprio(1);
#pragma unroll
  for (int c = 0; c < 4; ++c) {
    const int kr = c * 16 + lo;
    const int sw = kr & 7;
    const bf16x8 b0 =
        __builtin_bit_cast(bf16x8, *(const u32x4*)&Kl[kr * 64 + ((g ^ sw) << 3)]);
    const bf16x8 b1 =
        __builtin_bit_cast(bf16x8, *(const u32x4*)&Kl[kr * 64 + (((4 + g) ^ sw) << 3)]);
    f32x4 z = {};
    z = __builtin_amdgcn_mfma_f32_16x16x32_bf16(aQ0, b0, z, 0, 0, 0);
    z = __builtin_amdgcn_mfma_f32_16x16x32_bf16(aQ1, b1, z, 0, 0, 0);
    s[c] = z;
  }
  __builtin_amdgcn_s_setprio(0);
  if (diag) {
#pragma unroll
    for (int c = 0; c < 4; ++c)
#pragma unroll
      for (int r = 0; r < 4; ++r)
        if ((c * 16 + lo) > (wq * 16 + g * 4 + r)) s[c][r] = -__builtin_inff();
  }
#pragma unroll
  for (int r = 0; r < 4; ++r) {
    float rm = fmaxf(fmaxf(s[0][r], s[1][r]), fmaxf(s[2][r], s[3][r]));
    rm = rmax16(rm);
    const float mn = fmaxf(m[r], rm);
    const float alpha = __expf(m[r] - mn);
    m[r] = mn;
    float rs = 0.f;
#pragma unroll
    for (int c = 0; c < 4; ++c) {
      const float p = __expf(s[c][r] - mn);
      s[c][r] = p;
      rs += p;
    }
    rs = rsum16(rs);
    lsum[r] = lsum[r] * alpha + rs;
#pragma unroll
    for (int nt = 0; nt < 4; ++nt) oacc[nt][r] *= alpha;
#pragma unroll
    for (int c = 0; c < 4; ++c) Pw[(g * 4 + r) * 72 + c * 16 + lo] = f2bf(s[c][r]);
  }
  __builtin_amdgcn_s_setprio(1);
#pragma unroll
  for (int kc = 0; kc < 2; ++kc) {
    const bf16x8 aP =
        __builtin_bit_cast(bf16x8, *(const u32x4*)&Pw[lo * 72 + kc * 32 + 8 * g]);
#pragma unroll
    for (int nt = 0; nt < 4; ++nt) {
      const int d = nt * 16 + lo;
      const bf16x8 bV = __builtin_bit_cast(
          bf16x8, *(const u32x4*)&Vl[d * 64 + (((kc * 4 + g) ^ (d & 7)) << 3)]);
      oacc[nt] = __builtin_amdgcn_mfma_f32_16x16x32_bf16(aP, bV, oacc[nt], 0, 0, 0);
    }
  }
  __builtin_amdgcn_s_setprio(0);
}

// Block (j, bh): q-blocks qa=j, qb=31-j.
//  waves 4-7 (side1): q-block qb, K-tiles 0..15          (16 steps)
//  waves 0-3 (side0): q-block qa, K-tiles 0..qa, then
//                     q-block qb, K-tiles 16..qb          (17 steps)
// Partials for qb strips merged at the end via LDS.
__global__ __launch_bounds__(512, 4) void flash_attn(
    const unsigned short* __restrict__ Q, const unsigned short* __restrict__ K,
    const unsigned short* __restrict__ VT, unsigned short* __restrict__ O) {
  __shared__ unsigned short Kb[2][4096];
  __shared__ unsigned short Vb[2][4096];
  __shared__ unsigned short Pl[8][1152];
  const int t = threadIdx.x;
  const int lane = t & 63, w = t >> 6;
  const int lo = lane & 15, g = lane >> 4;
  const int bh = blockIdx.y;
  const int j = blockIdx.x;
  const int qa = j, qb = 31 - j;
  const unsigned short* Qh = Q + (size_t)bh * S_SZ * DK;
  const unsigned short* Kh = K + (size_t)bh * S_SZ * DK;
  const unsigned short* Vh = VT + (size_t)bh * DK * S_SZ;

  const int wq = w & 3;
  const bool s1 = w >= 4;
  const int rowMain = (s1 ? qb : qa) * 64 + wq * 16;  // state-A strip
  const int rowB = qb * 64 + wq * 16;                 // side0 phase-B strip
  const bf16x8 aQ0 = ld16g(Qh + (size_t)(rowMain + lo) * DK + 8 * g);
  const bf16x8 aQ1 = ld16g(Qh + (size_t)(rowMain + lo) * DK + 32 + 8 * g);
  bf16x8 aQB0 = aQ0, aQB1 = aQ1;
  if (!s1) {
    aQB0 = ld16g(Qh + (size_t)(rowB + lo) * DK + 8 * g);
    aQB1 = ld16g(Qh + (size_t)(rowB + lo) * DK + 32 + 8 * g);
  }

  float mA[4], lA[4], mB[4], lB[4];
  f32x4 oA[4] = {}, oB[4] = {};
#pragma unroll
  for (int r = 0; r < 4; ++r) {
    mA[r] = mB[r] = -__builtin_inff();
    lA[r] = lB[r] = 0.f;
  }
  unsigned short* Pw = &Pl[w][0];

  for (int i = 0; i <= 16; ++i) {
    if (i < 16) {  // side1 tile i into slot1
      stage8(Kh + (size_t)i * 64 * DK, DK, Kb[1], t);
      stage8(Vh + i * 64, S_SZ, Vb[1], t);
    }
    if (i > qa) {  // side0 tile 15+i-qa into slot0
      const int t0c = 15 + i - qa;
      stage8(Kh + (size_t)t0c * 64 * DK, DK, Kb[0], t);
      stage8(Vh + t0c * 64, S_SZ, Vb[0], t);
    }
    __syncthreads();
    if (s1) {
      if (i < 16) {
        attn_step(Kb[1], Vb[1], Pw, aQ0, aQ1, false, wq, lo, g, mA, lA, oA);
      } else {
        // publish partial (m,l,o) for merge
        float* ml = (float*)Pw;
#pragma unroll
        for (int r = 0; r < 4; ++r) {
          ml[r * 64 + lane] = mA[r];
          ml[(4 + r) * 64 + lane] = lA[r];
        }
        float* obase = (w < 6) ? ((float*)&Kb[1][0]) + (w - 4) * 1024
                               : ((float*)&Vb[1][0]) + (w - 6) * 1024;
#pragma unroll
        for (int nt = 0; nt < 4; ++nt)
#pragma unroll
          for (int r = 0; r < 4; ++r) obase[(nt * 4 + r) * 64 + lane] = oA[nt][r];
      }
    } else {
      if (i <= qa)
        attn_step(Kb[1], Vb[1], Pw, aQ0, aQ1, i == qa, wq, lo, g, mA, lA, oA);
      else
        attn_step(Kb[0], Vb[0], Pw, aQB0, aQB1, i == 16, wq, lo, g, mB, lB, oB);
    }
    __syncthreads();
  }

  if (!s1) {
    const int b = bh >> 4, h = bh & 15;
    // state A (q-block qa) complete -> write
#pragma unroll
    for (int r = 0; r < 4; ++r) {
      const float inv = 1.0f / (lA[r] + 1e-8f);
      const size_t base = ((size_t)(b * S_SZ + rowMain + g * 4 + r)) * 1024 + h * DK;
#pragma unroll
      for (int nt = 0; nt < 4; ++nt) O[base + nt * 16 + lo] = f2bf(oA[nt][r] * inv);
    }
    // merge state B (tiles 16..qb) with side1 partial (tiles 0..15) -> write
    const float* ml = (const float*)&Pl[w + 4][0];
    const float* obase = (w < 2) ? ((const float*)&Kb[1][0]) + w * 1024
                                 : ((const float*)&Vb[1][0]) + (w - 2) * 1024;
#pragma unroll
    for (int r = 0; r < 4; ++r) {
      const float m1 = ml[r * 64 + lane], l1 = ml[(4 + r) * 64 + lane];
      const float mh = fmaxf(mB[r], m1);
      const float a0 = __expf(mB[r] - mh), a1 = __expf(m1 - mh);
      const float linv = 1.0f / (lB[r] * a0 + l1 * a1 + 1e-8f);
      const size_t base = ((size_t)(b * S_SZ + rowB + g * 4 + r)) * 1024 + h * DK;
#pragma unroll
      for (int nt = 0; nt < 4; ++nt)
        O[base + nt * 16 + lo] =
            f2bf((oB[nt][r] * a0 + obase[(nt * 4 + r) * 64 + lane] * a1) * linv);
    }
  }
}

extern "C" void kernel_launch(void* const* d_in, const int* in_sizes, int n_in,
                              void* d_out, int out_size, void* d_ws, size_t ws_size,
                              hipStream_t stream) {
  const float* x = (const float*)d_in[0];
  const float* w_qkv = (const float*)d_in[1];
  const float* b_qkv = (const float*)d_in[2];
  const float* w_out = (const float*)d_in[3];
  const float* b_out = (const float*)d_in[4];
  float* out = (float*)d_out;

  char* ws = (char*)d_ws;
  unsigned short* xb = (unsigned short*)(ws);
  unsigned short* wqb = (unsigned short*)(ws + 8388608);
  unsigned short* wob = (unsigned short*)(ws + 14680064);
  unsigned short* qkv = (unsigned short*)(ws + 16777216);
  unsigned short* kb = (unsigned short*)(ws + 41943040);
  unsigned short* vt = (unsigned short*)(ws + 50331648);
  unsigned short* qb = xb;
  unsigned short* ob = qkv;

  cvt_bf16<<<4096, 256, 0, stream>>>(x, w_qkv, w_out, xb, wqb, wob);
  {
    dim3 grid(3072 / 128, 4096 / 128);
    gemm_bf16<true><<<grid, 256, 0, stream>>>(xb, wqb, b_qkv, qkv, 3072, 1024);
  }
  rope_scatter<<<(2 * NH * S_SZ * 32) / 256, 256, 0, stream>>>(qkv, qb, kb, vt);
  {
    dim3 grid(16, 2 * NH);
    flash_attn<<<grid, 512, 0, stream>>>(qb, kb, vt, ob);
  }
  {
    dim3 grid(1024 / 128, 4096 / 128);
    gemm_bf16<false><<<grid, 256, 0, stream>>>(ob, wob, b_out, out, 1024, 1024);
  }
}